// Round 4
// baseline (8345.621 us; speedup 1.0000x reference)
//
#include <hip/hip_runtime.h>
#include <math.h>

#define Hn 50
#define HP 56            // padded k extent
#define Dn 8
#define Tn 512
#define BB 8             // batch rows per block
#define KHC 7            // float4 chunks per k-half
#define KHW (KHC * 4)    // 28 k's per half
#define NBLK (2048 / BB) // 256 blocks = 1 per CU

__device__ __forceinline__ float sigmoidf_(float x) {
    return 1.0f / (1.0f + __expf(-x));
}
__device__ __forceinline__ float tanhf_(float x) {
    float a = fabsf(x);
    float e = __expf(-2.0f * a);
    float r = (1.0f - e) / (1.0f + e);
    return copysignf(r, x);
}

// Persistent 2-layer LSTM, 256 threads (4 waves = 1 wave/EU) so
// __launch_bounds__(256,1) unlocks the full 256-VGPR budget.
// (512-thread blocks force 2 waves/EU co-residency -> 128-VGPR cap ->
// the spill storms of rounds 1-3.)
// Thread t: kh = t>>7 (k-half, 28 k's), owns padded gate-rows sub=t&127
// (gates 0-1) and sub+128 (gates 2-3) -> each h-broadcast float4 feeds
// 8 FMAs. Weights: 176 floats in VGPRs, loaded once.
__global__ __launch_bounds__(256, 1) void lstm2_kernel(
    const float* __restrict__ x,
    const float* __restrict__ Wih0, const float* __restrict__ Whh0,
    const float* __restrict__ bih0, const float* __restrict__ bhh0,
    const float* __restrict__ Wih1, const float* __restrict__ Whh1,
    const float* __restrict__ bih1, const float* __restrict__ bhh1,
    const float* __restrict__ Wlin, const float* __restrict__ blin,
    float* __restrict__ out)
{
    const int tid = threadIdx.x;        // 0..255
    const int b0  = blockIdx.x * BB;
    const int kh  = tid >> 7;           // 0,1 : k in [kh*28, kh*28+28)
    const int sub = tid & 127;
    const int rA  = sub;                // padded row, gates 0..1
    const int rB  = sub + 128;          // padded row, gates 2..3
    const int kbase = kh * KHW;

    __shared__ __align__(16) float h0s[BB][HP];     // [b][k], pad zeroed
    __shared__ __align__(16) float h1s[BB][HP];
    __shared__ __align__(16) float gP[2][256][BB];  // [kh][row][b]
    __shared__ __align__(16) float xss[2][BB][Dn];  // double-buffered x_t
    __shared__ float bsum0[256];                    // combined bias, layer 0
    __shared__ float bsum1[256];                    // combined bias, layer 1

    // ---- weight slices in registers (loaded once, never spilled) ----
    float wa0[KHW], wb0[KHW], wc0[KHW];   // row rA : Whh0 / Wih1 / Whh1
    float wa1[KHW], wb1[KHW], wc1[KHW];   // row rB
    float wx0[4], wx1[4];                 // Wih0 k-split halves
    {
        const int gA = rA >> 6, cA = rA & 63; const bool reA = (cA < Hn);
        const int gB = rB >> 6, cB = rB & 63; const bool reB = (cB < Hn);
        const int growA = gA * Hn + cA;
        const int growB = gB * Hn + cB;
        #pragma unroll
        for (int j = 0; j < KHW; ++j) {
            const int k = kbase + j;
            const bool kr = (k < Hn);
            wa0[j] = (reA && kr) ? Whh0[growA * Hn + k] : 0.f;
            wb0[j] = (reA && kr) ? Wih1[growA * Hn + k] : 0.f;
            wc0[j] = (reA && kr) ? Whh1[growA * Hn + k] : 0.f;
            wa1[j] = (reB && kr) ? Whh0[growB * Hn + k] : 0.f;
            wb1[j] = (reB && kr) ? Wih1[growB * Hn + k] : 0.f;
            wc1[j] = (reB && kr) ? Whh1[growB * Hn + k] : 0.f;
        }
        #pragma unroll
        for (int d = 0; d < 4; ++d) {
            wx0[d] = reA ? Wih0[growA * Dn + kh * 4 + d] : 0.f;
            wx1[d] = reB ? Wih0[growB * Dn + kh * 4 + d] : 0.f;
        }
    }

    // ---- biases to LDS; zero h-state (incl. pad); stage x(t=0) ----
    {
        const int g = tid >> 6, c = tid & 63;
        float v0 = 0.f, v1 = 0.f;
        if (c < Hn) {
            v0 = bih0[g * Hn + c] + bhh0[g * Hn + c];
            v1 = bih1[g * Hn + c] + bhh1[g * Hn + c];
        }
        bsum0[tid] = v0; bsum1[tid] = v1;
    }
    for (int i = tid; i < BB * HP; i += 256) {
        ((float*)h0s)[i] = 0.f;
        ((float*)h1s)[i] = 0.f;
    }
    if (tid < 16) {
        const float4 v = *(const float4*)(x + (size_t)(b0 + (tid >> 1)) * Tn * Dn
                                            + (size_t)(tid & 1) * 4);
        *(float4*)&xss[0][tid >> 1][(tid & 1) * 4] = v;
    }
    __syncthreads();

    // ---- activation mapping: thread t<200: cell=t>>2, two b's = (t&3)*2,+1
    const int cellA = tid >> 2;
    const int bA1 = (tid & 3) * 2, bA2 = bA1 + 1;
    const bool actT = (tid < Hn * 4);   // 200 threads
    float c0a = 0.f, c0b = 0.f, c1a = 0.f, c1b = 0.f;

    for (int t = 0; t < Tn; ++t) {
        const int p = t & 1;

        // x(t+1) prefetch issue (threads 0..15)
        float4 xp;
        if (tid < 16 && t + 1 < Tn) {
            xp = *(const float4*)(x + (size_t)(b0 + (tid >> 1)) * Tn * Dn
                                    + (size_t)(t + 1) * Dn + (size_t)(tid & 1) * 4);
        }

        // ---- phase 1: accA = wx.x + wa.h0 ; accC = wc.h1 (k-partials) ----
        float accA0[BB], accA1[BB], accC0[BB], accC1[BB];
        #pragma unroll
        for (int b = 0; b < BB; ++b) {
            const float4 xv = *(const float4*)&xss[p][b][kh * 4];
            accA0[b] = wx0[0]*xv.x + wx0[1]*xv.y + wx0[2]*xv.z + wx0[3]*xv.w;
            accA1[b] = wx1[0]*xv.x + wx1[1]*xv.y + wx1[2]*xv.z + wx1[3]*xv.w;
            accC0[b] = 0.f; accC1[b] = 0.f;
        }
        #pragma unroll
        for (int c = 0; c < KHC; ++c) {
            #pragma unroll
            for (int b = 0; b < BB; ++b) {
                const float4 h0v = *(const float4*)&h0s[b][kbase + c * 4];  // broadcast
                const float4 h1v = *(const float4*)&h1s[b][kbase + c * 4];
                accA0[b] += wa0[c*4+0]*h0v.x + wa0[c*4+1]*h0v.y
                          + wa0[c*4+2]*h0v.z + wa0[c*4+3]*h0v.w;
                accA1[b] += wa1[c*4+0]*h0v.x + wa1[c*4+1]*h0v.y
                          + wa1[c*4+2]*h0v.z + wa1[c*4+3]*h0v.w;
                accC0[b] += wc0[c*4+0]*h1v.x + wc0[c*4+1]*h1v.y
                          + wc0[c*4+2]*h1v.z + wc0[c*4+3]*h1v.w;
                accC1[b] += wc1[c*4+0]*h1v.x + wc1[c*4+1]*h1v.y
                          + wc1[c*4+2]*h1v.z + wc1[c*4+3]*h1v.w;
            }
        }
        *(float4*)&gP[kh][rA][0] = make_float4(accA0[0], accA0[1], accA0[2], accA0[3]);
        *(float4*)&gP[kh][rA][4] = make_float4(accA0[4], accA0[5], accA0[6], accA0[7]);
        *(float4*)&gP[kh][rB][0] = make_float4(accA1[0], accA1[1], accA1[2], accA1[3]);
        *(float4*)&gP[kh][rB][4] = make_float4(accA1[4], accA1[5], accA1[6], accA1[7]);
        __syncthreads();

        // ---- layer-0 activations (two states per thread) ----
        if (actT) {
            const int ci = cellA;
            const float bi = bsum0[ci], bf = bsum0[64+ci],
                        bg = bsum0[128+ci], bo = bsum0[192+ci];
            {
                const float gi = gP[0][      ci][bA1] + gP[1][      ci][bA1] + bi;
                const float gf = gP[0][ 64 + ci][bA1] + gP[1][ 64 + ci][bA1] + bf;
                const float gg = gP[0][128 + ci][bA1] + gP[1][128 + ci][bA1] + bg;
                const float go = gP[0][192 + ci][bA1] + gP[1][192 + ci][bA1] + bo;
                c0a = sigmoidf_(gf) * c0a + sigmoidf_(gi) * tanhf_(gg);
                h0s[bA1][ci] = sigmoidf_(go) * tanhf_(c0a);
            }
            {
                const float gi = gP[0][      ci][bA2] + gP[1][      ci][bA2] + bi;
                const float gf = gP[0][ 64 + ci][bA2] + gP[1][ 64 + ci][bA2] + bf;
                const float gg = gP[0][128 + ci][bA2] + gP[1][128 + ci][bA2] + bg;
                const float go = gP[0][192 + ci][bA2] + gP[1][192 + ci][bA2] + bo;
                c0b = sigmoidf_(gf) * c0b + sigmoidf_(gi) * tanhf_(gg);
                h0s[bA2][ci] = sigmoidf_(go) * tanhf_(c0b);
            }
        }
        __syncthreads();

        // ---- phase 2: accC += wb . h0_new ----
        #pragma unroll
        for (int c = 0; c < KHC; ++c) {
            #pragma unroll
            for (int b = 0; b < BB; ++b) {
                const float4 h0v = *(const float4*)&h0s[b][kbase + c * 4];
                accC0[b] += wb0[c*4+0]*h0v.x + wb0[c*4+1]*h0v.y
                          + wb0[c*4+2]*h0v.z + wb0[c*4+3]*h0v.w;
                accC1[b] += wb1[c*4+0]*h0v.x + wb1[c*4+1]*h0v.y
                          + wb1[c*4+2]*h0v.z + wb1[c*4+3]*h0v.w;
            }
        }
        *(float4*)&gP[kh][rA][0] = make_float4(accC0[0], accC0[1], accC0[2], accC0[3]);
        *(float4*)&gP[kh][rA][4] = make_float4(accC0[4], accC0[5], accC0[6], accC0[7]);
        *(float4*)&gP[kh][rB][0] = make_float4(accC1[0], accC1[1], accC1[2], accC1[3]);
        *(float4*)&gP[kh][rB][4] = make_float4(accC1[4], accC1[5], accC1[6], accC1[7]);
        __syncthreads();

        // ---- layer-1 activations + x(t+1) stage ----
        if (actT) {
            const int ci = cellA;
            const float bi = bsum1[ci], bf = bsum1[64+ci],
                        bg = bsum1[128+ci], bo = bsum1[192+ci];
            {
                const float gi = gP[0][      ci][bA1] + gP[1][      ci][bA1] + bi;
                const float gf = gP[0][ 64 + ci][bA1] + gP[1][ 64 + ci][bA1] + bf;
                const float gg = gP[0][128 + ci][bA1] + gP[1][128 + ci][bA1] + bg;
                const float go = gP[0][192 + ci][bA1] + gP[1][192 + ci][bA1] + bo;
                c1a = sigmoidf_(gf) * c1a + sigmoidf_(gi) * tanhf_(gg);
                h1s[bA1][ci] = sigmoidf_(go) * tanhf_(c1a);
            }
            {
                const float gi = gP[0][      ci][bA2] + gP[1][      ci][bA2] + bi;
                const float gf = gP[0][ 64 + ci][bA2] + gP[1][ 64 + ci][bA2] + bf;
                const float gg = gP[0][128 + ci][bA2] + gP[1][128 + ci][bA2] + bg;
                const float go = gP[0][192 + ci][bA2] + gP[1][192 + ci][bA2] + bo;
                c1b = sigmoidf_(gf) * c1b + sigmoidf_(gi) * tanhf_(gg);
                h1s[bA2][ci] = sigmoidf_(go) * tanhf_(c1b);
            }
        }
        if (tid < 16 && t + 1 < Tn) {
            *(float4*)&xss[(t + 1) & 1][tid >> 1][(tid & 1) * 4] = xp;
        }
        __syncthreads();
    }

    // ---- head: out[b] = h1_last . Wlin + blin ----
    if (tid < BB) {
        float o = blin[0];
        #pragma unroll
        for (int k = 0; k < Hn; ++k) o += Wlin[k] * h1s[tid][k];
        out[b0 + tid] = o;
    }
}

extern "C" void kernel_launch(void* const* d_in, const int* in_sizes, int n_in,
                              void* d_out, int out_size, void* d_ws, size_t ws_size,
                              hipStream_t stream) {
    const float* x    = (const float*)d_in[0];
    const float* Wih0 = (const float*)d_in[1];
    const float* Whh0 = (const float*)d_in[2];
    const float* bih0 = (const float*)d_in[3];
    const float* bhh0 = (const float*)d_in[4];
    const float* Wih1 = (const float*)d_in[5];
    const float* Whh1 = (const float*)d_in[6];
    const float* bih1 = (const float*)d_in[7];
    const float* bhh1 = (const float*)d_in[8];
    const float* Wlin = (const float*)d_in[9];
    const float* blin = (const float*)d_in[10];
    float* out = (float*)d_out;

    lstm2_kernel<<<NBLK, 256, 0, stream>>>(x, Wih0, Whh0, bih0, bhh0,
                                           Wih1, Whh1, bih1, bhh1,
                                           Wlin, blin, out);
}

// Round 5
// 3662.580 us; speedup vs baseline: 2.2786x; 2.2786x over previous
//
#include <hip/hip_runtime.h>
#include <math.h>

#define Hn 50
#define Dn 8
#define Tn 512
#define BB 4          // batch rows per block
#define NBLK (2048 / BB)   // 512 blocks = 2 per CU

__device__ __forceinline__ float sigmoidf_(float x) {
    return 1.0f / (1.0f + __expf(-x));
}
__device__ __forceinline__ float tanhf_(float x) {
    float a = fabsf(x);
    float e = __expf(-2.0f * a);
    float r = (1.0f - e) / (1.0f + e);
    return copysignf(r, x);
}

// Persistent 2-layer LSTM — round-1 structure with the register cap fixed.
// 256 threads = 4 waves = 1 wave/EU, so __launch_bounds__(256,1) gives the
// full 256-VGPR budget: 158 weight floats + 8 accs + temps ~ 195 live fits
// with headroom (round 1 died at the 128 cap from min-waves=2; round 4
// died at ~290 live > 256). 2 blocks/CU (512-reg pool, 20 KB LDS) so one
// block's barriers hide under the other's compute.
// Thread t owns one padded gate row (gate = t>>6, cell = t&63; cell>=50
// is zero padding). All LDS layouts verified conflict-free in round 1.
__global__ __launch_bounds__(256, 1) void lstm2_kernel(
    const float* __restrict__ x,
    const float* __restrict__ Wih0, const float* __restrict__ Whh0,
    const float* __restrict__ bih0, const float* __restrict__ bhh0,
    const float* __restrict__ Wih1, const float* __restrict__ Whh1,
    const float* __restrict__ bih1, const float* __restrict__ bhh1,
    const float* __restrict__ Wlin, const float* __restrict__ blin,
    float* __restrict__ out)
{
    const int tid = threadIdx.x;      // 0..255
    const int b0 = blockIdx.x * BB;   // batch base for this block
    const int gate = tid >> 6;        // 0..3  (i,f,g,o)
    const int cell = tid & 63;        // 0..63 (50..63 = padding)
    const bool real = (cell < Hn);
    const int grow = gate * Hn + cell; // weight row (valid iff real)

    __shared__ __align__(16) float h0s[Hn][BB];     // [k][b] -> broadcast reads
    __shared__ __align__(16) float h1s[Hn][BB];
    __shared__ __align__(16) float g0s[256][BB];    // float4/lane, contiguous
    __shared__ __align__(16) float g1s[256][BB];
    __shared__ __align__(16) float xss[2][BB][Dn];  // double-buffered x_t

    // ---- weight rows in registers (persistent across all 512 steps) ----
    float wx[Dn], wa[Hn], wb[Hn], wc[Hn];
    float bias0 = 0.f, bias1 = 0.f;
    if (real) {
        #pragma unroll
        for (int d = 0; d < Dn; ++d) wx[d] = Wih0[grow * Dn + d];
        #pragma unroll
        for (int k = 0; k < Hn; ++k) {
            wa[k] = Whh0[grow * Hn + k];   // layer0 recurrent
            wb[k] = Wih1[grow * Hn + k];   // layer1 input
            wc[k] = Whh1[grow * Hn + k];   // layer1 recurrent
        }
        bias0 = bih0[grow] + bhh0[grow];
        bias1 = bih1[grow] + bhh1[grow];
    } else {
        #pragma unroll
        for (int d = 0; d < Dn; ++d) wx[d] = 0.f;
        #pragma unroll
        for (int k = 0; k < Hn; ++k) { wa[k] = 0.f; wb[k] = 0.f; wc[k] = 0.f; }
    }

    // ---- activation mapping: 200 threads own one (cell,b) state ----
    const int cellA = tid >> 2;       // 0..63 (valid 0..49)
    const int bA = tid & 3;
    const bool actT = (tid < Hn * BB);  // 200 state-owning threads
    float c0 = 0.f, c1 = 0.f;           // cell state in registers

    if (actT) { h0s[cellA][bA] = 0.f; h1s[cellA][bA] = 0.f; }
    // stage x for t=0
    if (tid < 8) {
        const float4 v = *(const float4*)(x + (size_t)(b0 + (tid >> 1)) * Tn * Dn
                                            + (size_t)(tid & 1) * 4);
        *(float4*)&xss[0][tid >> 1][(tid & 1) * 4] = v;
    }
    __syncthreads();

    for (int t = 0; t < Tn; ++t) {
        const int p = t & 1;

        // issue x(t+1) prefetch early so it overlaps phases 1-3
        float4 xp;
        if (tid >= 248 && t + 1 < Tn) {   // idle padding lanes of wave 3
            const int i = tid - 248;      // 0..7
            xp = *(const float4*)(x + (size_t)(b0 + (i >> 1)) * Tn * Dn
                                    + (size_t)(t + 1) * Dn + (size_t)(i & 1) * 4);
        }

        // ---- phase 1: accA = Wih0*x_t + Whh0*h0 + b0 ; accC = Whh1*h1 ----
        float accA[BB], accC[BB];
        {
            const float4 xa = *(const float4*)&xss[p][0][0];  // b-major x stage
            // per-b x dot (x stored [b][d]; read per b)
        }
        #pragma unroll
        for (int b = 0; b < BB; ++b) { accA[b] = bias0; accC[b] = 0.f; }
        #pragma unroll
        for (int b = 0; b < BB; ++b) {
            const float4 xa = *(const float4*)&xss[p][b][0];
            const float4 xb = *(const float4*)&xss[p][b][4];
            accA[b] += wx[0]*xa.x + wx[1]*xa.y + wx[2]*xa.z + wx[3]*xa.w
                     + wx[4]*xb.x + wx[5]*xb.y + wx[6]*xb.z + wx[7]*xb.w;
        }
        #pragma unroll
        for (int k = 0; k < Hn; ++k) {
            const float4 hv0 = *(const float4*)&h0s[k][0];  // broadcast read
            const float4 hv1 = *(const float4*)&h1s[k][0];
            accA[0] += wa[k] * hv0.x; accA[1] += wa[k] * hv0.y;
            accA[2] += wa[k] * hv0.z; accA[3] += wa[k] * hv0.w;
            accC[0] += wc[k] * hv1.x; accC[1] += wc[k] * hv1.y;
            accC[2] += wc[k] * hv1.z; accC[3] += wc[k] * hv1.w;
        }
        *(float4*)&g0s[tid][0] = make_float4(accA[0], accA[1], accA[2], accA[3]);
        __syncthreads();

        // ---- layer-0 activations ----
        if (actT) {
            const float gi = g0s[cellA][bA];
            const float gf = g0s[64 + cellA][bA];
            const float gg = g0s[128 + cellA][bA];
            const float go = g0s[192 + cellA][bA];
            const float iv = sigmoidf_(gi);
            const float fv = sigmoidf_(gf);
            const float gv = tanhf_(gg);
            const float ov = sigmoidf_(go);
            c0 = fv * c0 + iv * gv;
            h0s[cellA][bA] = ov * tanhf_(c0);   // stride-1 in lane
        }
        __syncthreads();

        // ---- phase 2: accB = Wih1*h0_new + accC + b1 ----
        float accB[BB];
        #pragma unroll
        for (int b = 0; b < BB; ++b) accB[b] = accC[b] + bias1;
        #pragma unroll
        for (int k = 0; k < Hn; ++k) {
            const float4 hv0 = *(const float4*)&h0s[k][0];
            accB[0] += wb[k] * hv0.x; accB[1] += wb[k] * hv0.y;
            accB[2] += wb[k] * hv0.z; accB[3] += wb[k] * hv0.w;
        }
        *(float4*)&g1s[tid][0] = make_float4(accB[0], accB[1], accB[2], accB[3]);
        __syncthreads();

        // ---- layer-1 activations + x(t+1) stage ----
        if (actT) {
            const float gi = g1s[cellA][bA];
            const float gf = g1s[64 + cellA][bA];
            const float gg = g1s[128 + cellA][bA];
            const float go = g1s[192 + cellA][bA];
            const float iv = sigmoidf_(gi);
            const float fv = sigmoidf_(gf);
            const float gv = tanhf_(gg);
            const float ov = sigmoidf_(go);
            c1 = fv * c1 + iv * gv;
            h1s[cellA][bA] = ov * tanhf_(c1);
        }
        if (tid >= 248 && t + 1 < Tn) {
            const int i = tid - 248;
            *(float4*)&xss[(t + 1) & 1][i >> 1][(i & 1) * 4] = xp;
        }
        __syncthreads();
    }

    // ---- head: out[b] = h1_last . Wlin + blin ----
    if (tid < BB) {
        float o = blin[0];
        #pragma unroll
        for (int k = 0; k < Hn; ++k) o += Wlin[k] * h1s[k][tid];
        out[b0 + tid] = o;
    }
}

extern "C" void kernel_launch(void* const* d_in, const int* in_sizes, int n_in,
                              void* d_out, int out_size, void* d_ws, size_t ws_size,
                              hipStream_t stream) {
    const float* x    = (const float*)d_in[0];
    const float* Wih0 = (const float*)d_in[1];
    const float* Whh0 = (const float*)d_in[2];
    const float* bih0 = (const float*)d_in[3];
    const float* bhh0 = (const float*)d_in[4];
    const float* Wih1 = (const float*)d_in[5];
    const float* Whh1 = (const float*)d_in[6];
    const float* bih1 = (const float*)d_in[7];
    const float* bhh1 = (const float*)d_in[8];
    const float* Wlin = (const float*)d_in[9];
    const float* blin = (const float*)d_in[10];
    float* out = (float*)d_out;

    lstm2_kernel<<<NBLK, 256, 0, stream>>>(x, Wih0, Whh0, bih0, bhh0,
                                           Wih1, Whh1, bih1, bhh1,
                                           Wlin, blin, out);
}

// Round 6
// 2952.419 us; speedup vs baseline: 2.8267x; 1.2405x over previous
//
#include <hip/hip_runtime.h>
#include <math.h>

#define Hn 50
#define Dn 8
#define Tn 512
#define BB 4            // batch rows per block
#define KC 13           // k-chunk per wave (4 waves x 13 = 52 >= 50)
#define NBLK (2048 / BB)

__device__ __forceinline__ float sigmoidf_(float x) {
    return 1.0f / (1.0f + __expf(-x));
}
__device__ __forceinline__ float tanhf_(float x) {
    float a = fabsf(x);
    float e = __expf(-2.0f * a);
    float r = (1.0f - e) / (1.0f + e);
    return copysignf(r, x);
}
__device__ __forceinline__ float rlane(float v, int l) {
    return __int_as_float(__builtin_amdgcn_readlane(__float_as_int(v), l));
}

// Persistent 2-layer LSTM, readlane-distributed h.
// Round-5 was LDS-issue-bound (150 broadcast ds_read_b128/thread/step;
// DS pipe is per-CU). Here each wave loads the whole h-tile (lane k holds
// h[k][b0..3]) with ONE ds_read_b128, then v_readlane (VALU pipe) feeds
// the FMAs. Lane l owns the 4 gate rows (i,f,g,o) of cell l; wave w owns
// k-chunk [13w,13w+13). Weights 164 floats in regs; ~235 live total.
__global__ __launch_bounds__(256, 1) void lstm2_kernel(
    const float* __restrict__ x,
    const float* __restrict__ Wih0, const float* __restrict__ Whh0,
    const float* __restrict__ bih0, const float* __restrict__ bhh0,
    const float* __restrict__ Wih1, const float* __restrict__ Whh1,
    const float* __restrict__ bih1, const float* __restrict__ bhh1,
    const float* __restrict__ Wlin, const float* __restrict__ blin,
    float* __restrict__ out)
{
    const int tid  = threadIdx.x;       // 0..255
    const int b0   = blockIdx.x * BB;
    const int w    = tid >> 6;          // wave index -> k-chunk
    const int lane = tid & 63;          // cell owned by this lane
    const int kb   = w * KC;            // chunk base
    const bool realc = (lane < Hn);

    // LDS: h tiles (lane k holds h[k][b], 4 floats; padded to 256 floats
    // so the b128 tile read by lanes up to 63 stays in-bounds), and gate
    // partials gP[w][g][cell][b].
    __shared__ __align__(16) float h0s[256];
    __shared__ __align__(16) float h1s[256];
    __shared__ __align__(16) float gP[4][4][64][4];

    // ---- weight slices in registers ----
    float wa[4][KC], wb[4][KC], wc[4][KC], wx[4][2];
    #pragma unroll
    for (int g = 0; g < 4; ++g) {
        const int row = g * Hn + lane;          // valid iff realc
        #pragma unroll
        for (int j = 0; j < KC; ++j) {
            const int k = kb + j;
            const bool ok = realc && (k < Hn);
            wa[g][j] = ok ? Whh0[row * Hn + k] : 0.f;
            wb[g][j] = ok ? Wih1[row * Hn + k] : 0.f;
            wc[g][j] = ok ? Whh1[row * Hn + k] : 0.f;
        }
        #pragma unroll
        for (int d = 0; d < 2; ++d)
            wx[g][d] = realc ? Wih0[row * Dn + 2 * w + d] : 0.f;
    }

    // ---- activation mapping: tid<200 owns state (cell=tid>>2, b=tid&3) ----
    const int cA = tid >> 2, bA = tid & 3;
    const bool actT = (tid < Hn * BB);
    float bs0[4], bs1[4];
    #pragma unroll
    for (int g = 0; g < 4; ++g) {
        bs0[g] = actT ? (bih0[g * Hn + cA] + bhh0[g * Hn + cA]) : 0.f;
        bs1[g] = actT ? (bih1[g * Hn + cA] + bhh1[g * Hn + cA]) : 0.f;
    }
    float c0 = 0.f, c1 = 0.f;

    // zero h tiles (incl. pads read by the wide tile loads)
    h0s[tid] = 0.f;
    h1s[tid] = 0.f;

    // x for this wave: d in {2w, 2w+1}, all 4 b. Prefetched one step.
    float2 xc[BB], xn[BB];
    #pragma unroll
    for (int b = 0; b < BB; ++b)
        xc[b] = *(const float2*)(x + ((size_t)(b0 + b) * Tn + 0) * Dn + 2 * w);
    __syncthreads();

    for (int t = 0; t < Tn; ++t) {
        // issue next-step x loads early (latency hidden across the step)
        const int tn = (t + 1 < Tn) ? t + 1 : t;
        #pragma unroll
        for (int b = 0; b < BB; ++b)
            xn[b] = *(const float2*)(x + ((size_t)(b0 + b) * Tn + tn) * Dn + 2 * w);

        // ---- phase A: accA = Wih0.x + Whh0.h0 (k-chunk partials) ----
        const float4 h0t = *(const float4*)&h0s[lane * 4];   // whole tile
        const float4 h1t = *(const float4*)&h1s[lane * 4];   // h1(t-1), used in C
        float accA[4][BB];
        #pragma unroll
        for (int g = 0; g < 4; ++g) {
            #pragma unroll
            for (int b = 0; b < BB; ++b)
                accA[g][b] = wx[g][0] * ((const float*)&xc[b])[0]
                           + wx[g][1] * ((const float*)&xc[b])[1];
        }
        #pragma unroll
        for (int j = 0; j < KC; ++j) {
            const int kl = kb + j;
            float hv[BB];
            hv[0] = rlane(h0t.x, kl); hv[1] = rlane(h0t.y, kl);
            hv[2] = rlane(h0t.z, kl); hv[3] = rlane(h0t.w, kl);
            #pragma unroll
            for (int g = 0; g < 4; ++g)
                #pragma unroll
                for (int b = 0; b < BB; ++b)
                    accA[g][b] += wa[g][j] * hv[b];
        }
        #pragma unroll
        for (int g = 0; g < 4; ++g)
            *(float4*)&gP[w][g][lane][0] =
                make_float4(accA[g][0], accA[g][1], accA[g][2], accA[g][3]);
        __syncthreads();

        // ---- phase B: layer-0 activations ----
        if (actT) {
            float gv[4];
            #pragma unroll
            for (int g = 0; g < 4; ++g)
                gv[g] = gP[0][g][cA][bA] + gP[1][g][cA][bA]
                      + gP[2][g][cA][bA] + gP[3][g][cA][bA] + bs0[g];
            const float iv = sigmoidf_(gv[0]);
            const float fv = sigmoidf_(gv[1]);
            const float gg = tanhf_(gv[2]);
            const float ov = sigmoidf_(gv[3]);
            c0 = fv * c0 + iv * gg;
            h0s[tid] = ov * tanhf_(c0);     // tile slot (cA*4+bA) == tid
        }
        __syncthreads();

        // ---- phase C: accB = Wih1.h0new + Whh1.h1old ----
        const float4 h0nt = *(const float4*)&h0s[lane * 4];
        float accB[4][BB];
        #pragma unroll
        for (int g = 0; g < 4; ++g)
            #pragma unroll
            for (int b = 0; b < BB; ++b) accB[g][b] = 0.f;
        #pragma unroll
        for (int j = 0; j < KC; ++j) {
            const int kl = kb + j;
            float hv[BB], hw[BB];
            hv[0] = rlane(h0nt.x, kl); hv[1] = rlane(h0nt.y, kl);
            hv[2] = rlane(h0nt.z, kl); hv[3] = rlane(h0nt.w, kl);
            hw[0] = rlane(h1t.x, kl);  hw[1] = rlane(h1t.y, kl);
            hw[2] = rlane(h1t.z, kl);  hw[3] = rlane(h1t.w, kl);
            #pragma unroll
            for (int g = 0; g < 4; ++g)
                #pragma unroll
                for (int b = 0; b < BB; ++b)
                    accB[g][b] += wb[g][j] * hv[b] + wc[g][j] * hw[b];
        }
        #pragma unroll
        for (int g = 0; g < 4; ++g)
            *(float4*)&gP[w][g][lane][0] =
                make_float4(accB[g][0], accB[g][1], accB[g][2], accB[g][3]);
        __syncthreads();

        // ---- phase D: layer-1 activations ----
        if (actT) {
            float gv[4];
            #pragma unroll
            for (int g = 0; g < 4; ++g)
                gv[g] = gP[0][g][cA][bA] + gP[1][g][cA][bA]
                      + gP[2][g][cA][bA] + gP[3][g][cA][bA] + bs1[g];
            const float iv = sigmoidf_(gv[0]);
            const float fv = sigmoidf_(gv[1]);
            const float gg = tanhf_(gv[2]);
            const float ov = sigmoidf_(gv[3]);
            c1 = fv * c1 + iv * gg;
            h1s[tid] = ov * tanhf_(c1);
        }
        __syncthreads();

        #pragma unroll
        for (int b = 0; b < BB; ++b) xc[b] = xn[b];
    }

    // ---- head: out[b] = h1_last . Wlin + blin ----
    if (tid < BB) {
        float o = blin[0];
        #pragma unroll
        for (int k = 0; k < Hn; ++k) o += Wlin[k] * h1s[k * 4 + tid];
        out[b0 + tid] = o;
    }
}

extern "C" void kernel_launch(void* const* d_in, const int* in_sizes, int n_in,
                              void* d_out, int out_size, void* d_ws, size_t ws_size,
                              hipStream_t stream) {
    const float* x    = (const float*)d_in[0];
    const float* Wih0 = (const float*)d_in[1];
    const float* Whh0 = (const float*)d_in[2];
    const float* bih0 = (const float*)d_in[3];
    const float* bhh0 = (const float*)d_in[4];
    const float* Wih1 = (const float*)d_in[5];
    const float* Whh1 = (const float*)d_in[6];
    const float* bih1 = (const float*)d_in[7];
    const float* bhh1 = (const float*)d_in[8];
    const float* Wlin = (const float*)d_in[9];
    const float* blin = (const float*)d_in[10];
    float* out = (float*)d_out;

    lstm2_kernel<<<NBLK, 256, 0, stream>>>(x, Wih0, Whh0, bih0, bhh0,
                                           Wih1, Whh1, bih1, bhh1,
                                           Wlin, blin, out);
}